// Round 3
// baseline (23231.453 us; speedup 1.0000x reference)
//
#include <hip/hip_runtime.h>
#include <hip/hip_bf16.h>

// LSTM: B=128, T=1024, D=H=768.
// R3: coalesced blocked layouts + MFMA role swap (A=W from LDS, B=h/x from
// global) + batched inline-asm uncached loads for the recurrent h-read.
//   hTb[buf][kb][b][ko] (kb=k/8, ko=k%8) bf16  -> B-frag load = 16B/lane,
//   32 consecutive lanes contiguous (512B segments). Same for xTb[t][...].
//   D = W·h^T -> lane holds all 4 gates for (batch=lane&31, j) in acc -> no
//   LDS gate transpose.

typedef __attribute__((ext_vector_type(8))) short short8v;   // 8 bf16 = 4 VGPR
typedef __attribute__((ext_vector_type(16))) float f32x16;   // 32x32 acc

constexpr int B_ = 128, T_ = 1024, D_ = 768, H_ = 768;
constexpr int NWG = 96;          // j-groups (8 h-cols each)

constexpr size_t FLAGS_OFF = 0;                        // 4 bands * 96 ints
constexpr size_t HB_OFF    = 4096;                     // 2*96*128*8 bf16 = 393216 B
constexpr size_t BIAS_OFF  = HB_OFF + 393216;          // 3072 f32 = 12288 B
constexpr size_t WC_OFF    = BIAS_OFF + 12288;         // 96*2*32*768 bf16 = 9437184 B
constexpr size_t XT_OFF    = WC_OFF + 9437184;         // 1024*96*128*8 bf16 = 201326592 B
constexpr size_t WS_NEED   = XT_OFF + 201326592;       // ~211.2 MB

__device__ __forceinline__ unsigned short f2bf(float f) {
  union { float f; unsigned u; } v; v.f = f;
  unsigned r = v.u + 0x7FFF + ((v.u >> 16) & 1);       // RNE
  return (unsigned short)(r >> 16);
}
__device__ __forceinline__ float sigmf(float x) { return 1.0f / (1.0f + __expf(-x)); }
__device__ __forceinline__ float tanhf_(float x) {
  float ax = fabsf(x);
  float e = __expf(-2.0f * ax);
  float t = (1.0f - e) / (1.0f + e);
  return copysignf(t, x);
}

// ---------------- P1: x -> xTb[t][kb][b][ko] bf16, LDS-tiled transpose ----
__global__ void k_xT(const float* __restrict__ x, unsigned short* __restrict__ xTb) {
  __shared__ float tile[16][776];                      // padded vs bank conflicts
  const int t = blockIdx.x;
  const int tid = threadIdx.x;
  for (int chunk = 0; chunk < 8; ++chunk) {            // 16 batch rows per chunk
    #pragma unroll
    for (int i = 0; i < 12; ++i) {                     // 3072 float4 loads
      int id = i * 256 + tid;
      int bl = id / 192, d4 = id % 192;
      int b = chunk * 16 + bl;
      float4 v = *(const float4*)(x + ((size_t)b * T_ + t) * D_ + d4 * 4);
      *(float4*)&tile[bl][d4 * 4] = v;
    }
    __syncthreads();
    #pragma unroll
    for (int i = 0; i < 6; ++i) {                      // 1536 16B stores
      int id = i * 256 + tid;
      int kb = id >> 4, bl = id & 15;
      int b = chunk * 16 + bl;
      const float* src = &tile[bl][kb * 8];
      unsigned short tmp[8];
      #pragma unroll
      for (int k = 0; k < 8; ++k) tmp[k] = f2bf(src[k]);
      *(short8v*)(xTb + (((size_t)t * 96 + kb) * 128 + b) * 8) = *(short8v*)tmp;
    }
    __syncthreads();
  }
}

// ---------------- P2: weight slices, swizzled (unchanged image) ----------
// Wc chunk id = wj*6144 + src*3072 + r*96 + kcp ; each chunk = 8 bf16 (16B)
// LDS image per WG: [src(2)][r(32)][kc'(96)] ; kc' = kc ^ (r&15)
__global__ void k_prep_w(const float* __restrict__ wih, const float* __restrict__ whh,
                         unsigned short* __restrict__ Wc) {
  int id  = blockIdx.x * 256 + threadIdx.x;            // exactly 589824
  int wj  = id / 6144;
  int rem = id - wj * 6144;
  int src = rem / 3072; rem -= src * 3072;
  int r   = rem / 96;
  int kcp = rem - r * 96;
  int kc  = kcp ^ (r & 15);
  int grow = (r >> 3) * H_ + wj * 8 + (r & 7);         // gate*768 + j
  const float* W = (src == 0) ? whh : wih;
  const float* p = W + (size_t)grow * D_ + kc * 8;
  float4 v0 = *(const float4*)p;
  float4 v1 = *(const float4*)(p + 4);
  ushort4 o0 = {f2bf(v0.x), f2bf(v0.y), f2bf(v0.z), f2bf(v0.w)};
  ushort4 o1 = {f2bf(v1.x), f2bf(v1.y), f2bf(v1.z), f2bf(v1.w)};
  *(ushort4*)(Wc + (size_t)id * 8)     = o0;
  *(ushort4*)(Wc + (size_t)id * 8 + 4) = o1;
}

// ---------------- P3: bias, h0 -> blocked bf16 buf0, flags ----------------
__global__ void k_prep_s(const float* __restrict__ h0,
                         const float* __restrict__ bih, const float* __restrict__ bhh,
                         unsigned short* __restrict__ hb, float* __restrict__ bias_c,
                         int* __restrict__ flags) {
  int id = blockIdx.x * 256 + threadIdx.x;             // exactly 98304
  int b = id / 768, j = id - b * 768;
  hb[(size_t)(j >> 3) * 1024 + b * 8 + (j & 7)] = f2bf(h0[id]);   // buf0 blocked
  if (id < 3072) {
    int wj = id >> 5, r = id & 31;
    int grow = (r >> 3) * H_ + wj * 8 + (r & 7);
    bias_c[id] = bih[grow] + bhh[grow];
  }
  if (id < 384) flags[id] = 0;
}

// ---------------- main recurrent kernel ----------------
__launch_bounds__(256, 1)
__global__ void k_lstm(const unsigned short* __restrict__ xTb,
                       const unsigned short* __restrict__ Wc,
                       const float* __restrict__ bias_c,
                       const float* __restrict__ c0,
                       unsigned short* __restrict__ hb,   // [2][96][128][8] bf16
                       int* flags,                        // [4][96]
                       float* __restrict__ out,           // [128][1024][768]
                       float* __restrict__ hT,
                       float* __restrict__ cT) {
  __shared__ __align__(16) unsigned short Wl[2 * 32 * 768];   // 96 KB (swizzled)
  __shared__ float bias_l[32];

  const int wj   = blockIdx.x;
  const int tid  = threadIdx.x;
  const int wave = tid >> 6;          // band: batch rows wave*32..+32
  const int lane = tid & 63;
  const int col  = lane & 31;         // A-row (gaterow) / B-col (batch-in-band)
  const int kh   = lane >> 5;
  const int sw   = col & 15;

  { // stage weight slices (pre-swizzled in global -> linear copy)
    const short8v* s = (const short8v*)(Wc + (size_t)wj * 49152);
    short8v* d = (short8v*)Wl;
    for (int i = tid; i < 6144; i += 256) d[i] = s[i];
    if (tid < 32) bias_l[tid] = bias_c[wj * 32 + tid];
  }
  __syncthreads();

  const int bg = wave * 32 + col;     // global batch row (B-frag col)
  const int jg = wj * 8 + 4 * kh;     // global h col base (4 cols per lane)

  float c_r[4];
  {
    float4 v = *(const float4*)(c0 + (size_t)bg * H_ + jg);
    c_r[0] = v.x; c_r[1] = v.y; c_r[2] = v.z; c_r[3] = v.w;
  }

  const char* wlb = (const char*)Wl;
  const int wrow0 = col * 1536;             // W_hh A-row base (bytes)
  const int wrow1 = 49152 + col * 1536;     // W_ih A-row base

  int* fb = flags + wave * 96;
  const int i1 = lane;
  const int i2 = 64 + (lane & 31);

  // per-lane bias per acc slot: row r(q) = (q&3) + 8*(q>>2) + 4*kh
  float bias_r[16];
  #pragma unroll
  for (int q = 0; q < 16; ++q) bias_r[q] = bias_l[(q & 3) + 8 * (q >> 2) + 4 * kh];

  f32x16 acc;
  { // phase X for t=0 (acc starts at bias)
    #pragma unroll
    for (int q = 0; q < 16; ++q) acc[q] = bias_r[q];
    const unsigned short* xp = xTb + (size_t)kh * 1024 + bg * 8;
    #pragma unroll
    for (int f = 0; f < 48; ++f) {
      short8v w = *(const short8v*)(wlb + wrow1 + (((2 * f + kh) ^ sw) << 4));
      short8v xv = *(const short8v*)(xp + f * 2048);
      acc = __builtin_amdgcn_mfma_f32_32x32x16_bf16(w, xv, acc, 0, 0, 0);
    }
  }

  for (int t = 0; t < T_; ++t) {
    if (t > 0) {
      for (;;) {  // relaxed agent-scope polls read the coherence point
        int v0 = __hip_atomic_load(fb + i1, __ATOMIC_RELAXED, __HIP_MEMORY_SCOPE_AGENT);
        int v1 = __hip_atomic_load(fb + i2, __ATOMIC_RELAXED, __HIP_MEMORY_SCOPE_AGENT);
        if (__all((v0 >= t) && (v1 >= t))) break;
      }
      asm volatile("" ::: "memory");  // acquire compiler barrier
    }

    // phase H: batch-issue 48 coalesced uncached 16B loads, then MFMA chain
    short8v hfrag[48];
    {
      const unsigned short* hp =
          hb + (size_t)(t & 1) * 98304 + (size_t)kh * 1024 + bg * 8;
      #pragma unroll
      for (int f = 0; f < 48; ++f) {
        asm volatile("global_load_dwordx4 %0, %1, off sc0 sc1"
                     : "=v"(hfrag[f]) : "v"(hp + f * 2048));
      }
    }
    asm volatile("s_waitcnt vmcnt(0)" ::: "memory");
    __builtin_amdgcn_sched_barrier(0);
    #pragma unroll
    for (int f = 0; f < 48; ++f) {
      short8v w = *(const short8v*)(wlb + wrow0 + (((2 * f + kh) ^ sw) << 4));
      acc = __builtin_amdgcn_mfma_f32_32x32x16_bf16(w, hfrag[f], acc, 0, 0, 0);
    }

    // gating: acc[q] = gates[gate=q>>2][j = (q&3)+4kh][batch=bg]
    float hnew[4];
    #pragma unroll
    for (int m = 0; m < 4; ++m) {
      float gi = acc[m];
      float gf = acc[4 + m];
      float gg = acc[8 + m];
      float go = acc[12 + m];
      float cn = sigmf(gf) * c_r[m] + sigmf(gi) * tanhf_(gg);
      c_r[m] = cn;
      hnew[m] = sigmf(go) * tanhf_(cn);
    }

    // h exchange: coalesced 8B write-through store (agent scope)
    union { ushort4 s; unsigned long long u; } hv;
    hv.s = (ushort4){f2bf(hnew[0]), f2bf(hnew[1]), f2bf(hnew[2]), f2bf(hnew[3])};
    __hip_atomic_store(
        (unsigned long long*)(hb + (size_t)((t + 1) & 1) * 98304 +
                              (size_t)wj * 1024 + bg * 8 + 4 * kh),
        hv.u, __ATOMIC_RELAXED, __HIP_MEMORY_SCOPE_AGENT);

    // release: h stores acked at coherence point, then relaxed flag store
    asm volatile("s_waitcnt vmcnt(0)" ::: "memory");
    if (lane == 0)
      __hip_atomic_store(fb + wj, t + 1, __ATOMIC_RELAXED, __HIP_MEMORY_SCOPE_AGENT);

    // out stores AFTER the release (off the critical path)
    float4 ov = make_float4(hnew[0], hnew[1], hnew[2], hnew[3]);
    *(float4*)(out + ((size_t)bg * T_ + t) * H_ + jg) = ov;
    if (t == T_ - 1) {
      *(float4*)(hT + (size_t)bg * H_ + jg) = ov;
      float4 cv = make_float4(c_r[0], c_r[1], c_r[2], c_r[3]);
      *(float4*)(cT + (size_t)bg * H_ + jg) = cv;
    }

    // phase X for t+1 (cached coalesced loads), in the shadow
    if (t + 1 < T_) {
      #pragma unroll
      for (int q = 0; q < 16; ++q) acc[q] = bias_r[q];
      const unsigned short* xp =
          xTb + (size_t)(t + 1) * 98304 + (size_t)kh * 1024 + bg * 8;
      #pragma unroll
      for (int f = 0; f < 48; ++f) {
        short8v w = *(const short8v*)(wlb + wrow1 + (((2 * f + kh) ^ sw) << 4));
        short8v xv = *(const short8v*)(xp + f * 2048);
        acc = __builtin_amdgcn_mfma_f32_32x32x16_bf16(w, xv, acc, 0, 0, 0);
      }
    }
  }
}

extern "C" void kernel_launch(void* const* d_in, const int* in_sizes, int n_in,
                              void* d_out, int out_size, void* d_ws, size_t ws_size,
                              hipStream_t stream) {
  const float* x   = (const float*)d_in[0];
  const float* h0  = (const float*)d_in[1];
  const float* c0  = (const float*)d_in[2];
  const float* wih = (const float*)d_in[3];
  const float* whh = (const float*)d_in[4];
  const float* bih = (const float*)d_in[5];
  const float* bhh = (const float*)d_in[6];

  float* out = (float*)d_out;
  float* hT  = out + (size_t)B_ * T_ * H_;
  float* cT  = hT + (size_t)B_ * H_;

  if (ws_size < WS_NEED) return;  // visible failure instead of OOB corruption

  char* ws = (char*)d_ws;
  int*            flags = (int*)(ws + FLAGS_OFF);
  unsigned short* hb    = (unsigned short*)(ws + HB_OFF);
  float*          biasc = (float*)(ws + BIAS_OFF);
  unsigned short* Wc    = (unsigned short*)(ws + WC_OFF);
  unsigned short* xTp   = (unsigned short*)(ws + XT_OFF);

  k_xT<<<dim3(T_), dim3(256), 0, stream>>>(x, xTp);
  k_prep_w<<<dim3(589824 / 256), dim3(256), 0, stream>>>(wih, whh, Wc);
  k_prep_s<<<dim3((B_ * H_) / 256), dim3(256), 0, stream>>>(h0, bih, bhh, hb, biasc, flags);
  k_lstm<<<dim3(NWG), dim3(256), 0, stream>>>(xTp, Wc, biasc, c0, hb, flags, out, hT, cT);
}